// Round 2
// baseline (400.507 us; speedup 1.0000x reference)
//
#include <hip/hip_runtime.h>
#include <hip/hip_bf16.h>

// Problem constants: B=4, C=128, Cq=16, W=H=64, N=4096.
// ws layout (ushort): qT bf16 [4][4096][16] @0, kT bf16 [4][4096][16] @262144,
//                     v  bf16 [4][128][4096] @524288, inv fp32 [4][4096] @2621440
// d_out: out[4][128][4096] fp32, then attention[4][4096][4096] fp32

typedef __attribute__((ext_vector_type(8))) short short8;
typedef __attribute__((ext_vector_type(16))) float float16;
typedef __attribute__((ext_vector_type(4))) float floatx4;

__device__ __forceinline__ ushort f2bf(float f) {
  union { float f; uint u; } v; v.f = f;
  return (ushort)((v.u + 0x7FFFu + ((v.u >> 16) & 1u)) >> 16);  // RNE
}

// ---------------- Kernel 1: QKV projections (unchanged, verified) ----------
__global__ __launch_bounds__(512, 2) void qkv_kernel(
    const float* __restrict__ x,
    const float* __restrict__ wq, const float* __restrict__ bq,
    const float* __restrict__ wk, const float* __restrict__ bk,
    const float* __restrict__ wv, const float* __restrict__ bv,
    ushort* __restrict__ qT, ushort* __restrict__ kT, ushort* __restrict__ vo) {
  __shared__ float xs[128 * 64];
  const int nt = blockIdx.x, b = blockIdx.y;
  const int n0 = nt * 64;
  const float* xb = x + (size_t)b * 524288 + n0;
  for (int idx = threadIdx.x; idx < 8192; idx += 512) {
    int c = idx >> 6, n = idx & 63;
    xs[idx] = xb[(size_t)c * 4096 + n];
  }
  __syncthreads();
  const int n = threadIdx.x & 63;
  const int og = __builtin_amdgcn_readfirstlane((int)(threadIdx.x >> 6)); // 0..7
  float acc[20];
#pragma unroll
  for (int i = 0; i < 20; i++) {
    int o = og + 8 * i;
    acc[i] = (i < 2) ? bq[o] : (i < 4) ? bk[o - 16] : bv[o - 32];
  }
#pragma unroll 4
  for (int c = 0; c < 128; c++) {
    float xr = xs[c * 64 + n];
#pragma unroll
    for (int i = 0; i < 20; i++) {
      int o = og + 8 * i;
      const float* wr = (i < 2) ? (wq + o * 128)
                      : (i < 4) ? (wk + (o - 16) * 128)
                                : (wv + (o - 32) * 128);
      acc[i] += wr[c] * xr;
    }
  }
  const size_t pos = (size_t)b * 4096 + n0 + n;
#pragma unroll
  for (int i = 0; i < 20; i++) {
    int o = og + 8 * i;
    if (i < 2)      qT[pos * 16 + o]      = f2bf(acc[i]);
    else if (i < 4) kT[pos * 16 + o - 16] = f2bf(acc[i]);
    else vo[(size_t)b * 524288 + (size_t)(o - 32) * 4096 + n0 + n] = f2bf(acc[i]);
  }
}

// ---------------- Kernel 2: softmax denominators -> inv[4][4096] -----------
// 512 blocks x 256 thr. Block = (b, rb, half): 32 rows, S=rb+1 strips.
// Same E-MFMA + exp + shuffle-reduce as the verified phase 1; inv written to ws.
__global__ __launch_bounds__(256, 2) void denom_kernel(
    const ushort* __restrict__ qT, const ushort* __restrict__ kT,
    float* __restrict__ invw) {
  __shared__ float red[32][4];
  const int bx = blockIdx.x;
  const int b = bx & 3;
  const int v_ = bx >> 2;
  const int half = v_ & 1;
  const int u = v_ >> 1;
  const int rb = (u < 32) ? u : 95 - u;  // CU-mate load balancing (sum=63)
  const int S = rb + 1;
  const int lane = threadIdx.x & 63;
  const int w = __builtin_amdgcn_readfirstlane((int)(threadIdx.x >> 6));
  const int nblk = rb * 64 + half * 32;
  const int l31 = lane & 31;
  const int h = lane >> 5;
  const int hk = h * 8;
  const ushort* qb = qT + (size_t)b * 65536;
  const ushort* kb = kT + (size_t)b * 65536;
  const short8 qa = *(const short8*)(qb + (size_t)(nblk + l31) * 16 + hk);
  float16 zero16;
#pragma unroll
  for (int i = 0; i < 16; i++) zero16[i] = 0.f;

  float sume[16];
#pragma unroll
  for (int i = 0; i < 16; i++) sume[i] = 0.f;
  for (int s = w; s < S; s += 4) {
    const int m0 = s * 64;
#pragma unroll
    for (int mh = 0; mh < 2; mh++) {
      short8 kf = *(const short8*)(kb + (size_t)(m0 + mh * 32 + l31) * 16 + hk);
      float16 e = __builtin_amdgcn_mfma_f32_32x32x16_bf16(qa, kf, zero16, 0, 0, 0);
#pragma unroll
      for (int r = 0; r < 16; r++) sume[r] += __expf(e[r]);
    }
  }
#pragma unroll
  for (int r = 0; r < 16; r++) {
#pragma unroll
    for (int off = 1; off <= 16; off <<= 1)
      sume[r] += __shfl_xor(sume[r], off, 64);  // sum over 32 cols (l31 group)
  }
  if (l31 == 0) {
#pragma unroll
    for (int r = 0; r < 16; r++) {
      int row = (r & 3) + 8 * (r >> 2) + 4 * h;
      red[row][w] = sume[r];
    }
  }
  __syncthreads();
  if (w == 0 && l31 == 0) {
#pragma unroll
    for (int r = 0; r < 16; r++) {
      int row = (r & 3) + 8 * (r >> 2) + 4 * h;
      float4 p4 = *(const float4*)&red[row][0];
      invw[(size_t)b * 4096 + nblk + row] = 1.0f / (p4.x + p4.y + p4.z + p4.w);
    }
  }
}

// ---------------- Kernel 3: streaming attention writer ---------------------
// 1024 blocks x 256 thr, no LDS, no barriers. Block = (b, ch, rb, half):
// 32 rows x 2048 cols (col-half ch). Every block writes exactly 256 KB
// (p-values for valid strips in its col range + zeros for the masked rest),
// so HBM write traffic is perfectly byte-balanced. Nontemporal stores keep
// the 268 MB attn stream out of L2 (kT/v stay resident for K4).
__global__ __launch_bounds__(256, 4) void attn_write_kernel(
    const ushort* __restrict__ qT, const ushort* __restrict__ kT,
    const float* __restrict__ invw, float* __restrict__ attn) {
  const int bx = blockIdx.x;            // 0..1023
  const int b = bx & 3;
  const int ch = (bx >> 2) & 1;         // column half: cols [ch*2048, ch*2048+2048)
  const int v_ = bx >> 3;               // 0..127
  const int half = v_ & 1;
  const int u = v_ >> 1;                // 0..63
  const int rb = (u < 32) ? u : 95 - u; // 4-way CU-mate balance (sum=126)
  const int S = rb + 1;
  const int M = S * 64;
  const int lane = threadIdx.x & 63;
  const int w = __builtin_amdgcn_readfirstlane((int)(threadIdx.x >> 6));
  const int nblk = rb * 64 + half * 32;
  const int l31 = lane & 31;
  const int h = lane >> 5;
  const int hk = h * 8;
  const ushort* qb = qT + (size_t)b * 65536;
  const ushort* kb = kT + (size_t)b * 65536;
  float* ab = attn + (size_t)b * 16777216;

  const short8 qa = *(const short8*)(qb + (size_t)(nblk + l31) * 16 + hk);
  float inv_r[16];
#pragma unroll
  for (int r = 0; r < 16; r++) {
    int row = (r & 3) + 8 * (r >> 2) + 4 * h;
    inv_r[r] = invw[(size_t)b * 4096 + nblk + row];
  }
  float16 zero16;
#pragma unroll
  for (int i = 0; i < 16; i++) zero16[i] = 0.f;

  // valid strips inside this column half, distributed over the 4 waves
  const int sEnd = (S < ch * 32 + 32) ? S : (ch * 32 + 32);
  for (int s = ch * 32 + w; s < sEnd; s += 4) {
    const int m0 = s * 64;
#pragma unroll
    for (int mh = 0; mh < 2; mh++) {
      short8 kf = *(const short8*)(kb + (size_t)(m0 + mh * 32 + l31) * 16 + hk);
      float16 e = __builtin_amdgcn_mfma_f32_32x32x16_bf16(qa, kf, zero16, 0, 0, 0);
#pragma unroll
      for (int r = 0; r < 16; r++) {
        int row = (r & 3) + 8 * (r >> 2) + 4 * h;
        float p = __expf(e[r]) * inv_r[r];
        __builtin_nontemporal_store(
            p, &ab[(size_t)(nblk + row) * 4096 + m0 + mh * 32 + l31]);
      }
    }
  }

  // zero-fill the masked part of this column half (wave w: rows w*8..w*8+7)
  const int zc0 = (M > ch * 2048) ? M : ch * 2048;
  const int zc1 = (ch + 1) * 2048;
  if (zc0 < zc1) {
    const int Z4 = (zc1 - zc0) >> 2;
    const floatx4 z = {0.f, 0.f, 0.f, 0.f};
#pragma unroll
    for (int r = 0; r < 8; r++) {
      floatx4* dst = (floatx4*)(ab + (size_t)(nblk + w * 8 + r) * 4096 + zc0);
      for (int i4 = lane; i4 < Z4; i4 += 64)
        __builtin_nontemporal_store(z, &dst[i4]);
    }
  }
}

// ---------------- Kernel 4: PV accumulate + epilogue -----------------------
// 512 blocks x 256 thr. Verified phase-2 structure minus global attn stores,
// minus phase 1 (inv read from ws). Per super-step (4 strips): wave w
// recomputes E for strip s0+w, writes bf16 p to LDS slot w; barrier; all
// waves run PV MFMA over the 4 slots (c-quadrant = wave).
__global__ __launch_bounds__(256, 2) void pv_kernel(
    const ushort* __restrict__ qT, const ushort* __restrict__ kT,
    const ushort* __restrict__ vws, const float* __restrict__ invw,
    const float* __restrict__ x, const float* __restrict__ g,
    float* __restrict__ out) {
  __shared__ __align__(16) ushort Pt[4][32 * 72];
  const int bx = blockIdx.x;            // 0..511
  const int b = bx & 3;
  const int v_ = bx >> 2;               // 0..127
  const int half = v_ & 1;
  const int u = v_ >> 1;                // 0..63
  const int rb = (u < 32) ? u : 95 - u; // CU-mate load balancing
  const int S = rb + 1;
  const int lane = threadIdx.x & 63;
  const int w = __builtin_amdgcn_readfirstlane((int)(threadIdx.x >> 6));
  const int nblk = rb * 64 + half * 32;
  const int l31 = lane & 31;
  const int h = lane >> 5;
  const int hk = h * 8;
  const ushort* qb = qT + (size_t)b * 65536;
  const ushort* kb = kT + (size_t)b * 65536;
  const ushort* vp = vws + (size_t)b * 524288;

  const short8 qa = *(const short8*)(qb + (size_t)(nblk + l31) * 16 + hk);
  float inv_r[16];
#pragma unroll
  for (int r = 0; r < 16; r++) {
    int row = (r & 3) + 8 * (r >> 2) + 4 * h;
    inv_r[r] = invw[(size_t)b * 4096 + nblk + row];
  }
  float16 zero16;
#pragma unroll
  for (int i = 0; i < 16; i++) zero16[i] = 0.f;

  float16 acc = zero16;
  for (int s0 = 0; s0 < S; s0 += 4) {
    const int sl = (S - s0 < 4) ? (S - s0) : 4;
    if (w < sl) {
      const int m0 = (s0 + w) * 64;
      ushort* Pb = &Pt[w][0];
#pragma unroll
      for (int mh = 0; mh < 2; mh++) {
        short8 kf = *(const short8*)(kb + (size_t)(m0 + mh * 32 + l31) * 16 + hk);
        float16 e = __builtin_amdgcn_mfma_f32_32x32x16_bf16(qa, kf, zero16, 0, 0, 0);
#pragma unroll
        for (int r = 0; r < 16; r++) {
          int row = (r & 3) + 8 * (r >> 2) + 4 * h;
          float p = __expf(e[r]) * inv_r[r];
          Pb[row * 72 + mh * 32 + l31] = f2bf(p);
        }
      }
    }
    __syncthreads();
    for (int ss = 0; ss < sl; ss++) {
      const int m0 = (s0 + ss) * 64;
      const ushort* vrow = vp + (size_t)(w * 32 + l31) * 4096 + m0 + hk;
      const ushort* Pr = &Pt[ss][l31 * 72 + hk];
#pragma unroll
      for (int kk = 0; kk < 4; kk++) {
        short8 a  = *(const short8*)(vrow + kk * 16);
        short8 bf = *(const short8*)(Pr + kk * 16);
        acc = __builtin_amdgcn_mfma_f32_32x32x16_bf16(a, bf, acc, 0, 0, 0);
      }
    }
    __syncthreads();
  }

  // ---- Epilogue: out = gamma * acc + x ----
  const float gamma = g[0];
#pragma unroll
  for (int reg = 0; reg < 16; reg++) {
    int row = (reg & 3) + 8 * (reg >> 2) + 4 * h;  // C/D row map
    int c = w * 32 + row;
    int n = nblk + l31;                            // C/D col = lane&31
    size_t off = (size_t)b * 524288 + (size_t)c * 4096 + n;
    out[off] = gamma * acc[reg] + x[off];
  }
}

extern "C" void kernel_launch(void* const* d_in, const int* in_sizes, int n_in,
                              void* d_out, int out_size, void* d_ws, size_t ws_size,
                              hipStream_t stream) {
  const float* x  = (const float*)d_in[0];
  const float* wq = (const float*)d_in[1];
  const float* bq = (const float*)d_in[2];
  const float* wk = (const float*)d_in[3];
  const float* bk = (const float*)d_in[4];
  const float* wv = (const float*)d_in[5];
  const float* bv = (const float*)d_in[6];
  const float* gm = (const float*)d_in[7];
  float* out  = (float*)d_out;
  float* attn = out + 2097152;            // output 1: attention [4][4096][4096]
  ushort* qTw = (ushort*)d_ws;            // bf16 [4][4096][16]
  ushort* kTw = qTw + 262144;             // bf16 [4][4096][16]
  ushort* vws = qTw + 524288;             // bf16 [4][128][4096]
  float* invw = (float*)(qTw + 2621440);  // fp32 [4][4096]

  qkv_kernel<<<dim3(64, 4), 512, 0, stream>>>(x, wq, bq, wk, bk, wv, bv, qTw, kTw, vws);
  denom_kernel<<<dim3(512), 256, 0, stream>>>(qTw, kTw, invw);
  attn_write_kernel<<<dim3(1024), 256, 0, stream>>>(qTw, kTw, invw, attn);
  pv_kernel<<<dim3(512), 256, 0, stream>>>(qTw, kTw, vws, invw, x, gm, out);
}

// Round 3
// 400.506 us; speedup vs baseline: 1.0000x; 1.0000x over previous
//
#include <hip/hip_runtime.h>
#include <hip/hip_bf16.h>

// Problem constants: B=4, C=128, Cq=16, W=H=64, N=4096.
// ws layout (ushort): qT bf16 [4][4096][16] @0, kT bf16 [4][4096][16] @262144,
//                     v  bf16 [4][128][4096] @524288, inv fp32 [4][4096] @2621440
// d_out: out[4][128][4096] fp32, then attention[4][4096][4096] fp32

typedef __attribute__((ext_vector_type(8))) short short8;
typedef __attribute__((ext_vector_type(16))) float float16;
typedef __attribute__((ext_vector_type(4))) float floatx4;

__device__ __forceinline__ ushort f2bf(float f) {
  union { float f; uint u; } v; v.f = f;
  return (ushort)((v.u + 0x7FFFu + ((v.u >> 16) & 1u)) >> 16);  // RNE
}

// ---------------- Kernel 1: QKV projections (unchanged, verified) ----------
__global__ __launch_bounds__(512, 2) void qkv_kernel(
    const float* __restrict__ x,
    const float* __restrict__ wq, const float* __restrict__ bq,
    const float* __restrict__ wk, const float* __restrict__ bk,
    const float* __restrict__ wv, const float* __restrict__ bv,
    ushort* __restrict__ qT, ushort* __restrict__ kT, ushort* __restrict__ vo) {
  __shared__ float xs[128 * 64];
  const int nt = blockIdx.x, b = blockIdx.y;
  const int n0 = nt * 64;
  const float* xb = x + (size_t)b * 524288 + n0;
  for (int idx = threadIdx.x; idx < 8192; idx += 512) {
    int c = idx >> 6, n = idx & 63;
    xs[idx] = xb[(size_t)c * 4096 + n];
  }
  __syncthreads();
  const int n = threadIdx.x & 63;
  const int og = __builtin_amdgcn_readfirstlane((int)(threadIdx.x >> 6)); // 0..7
  float acc[20];
#pragma unroll
  for (int i = 0; i < 20; i++) {
    int o = og + 8 * i;
    acc[i] = (i < 2) ? bq[o] : (i < 4) ? bk[o - 16] : bv[o - 32];
  }
#pragma unroll 4
  for (int c = 0; c < 128; c++) {
    float xr = xs[c * 64 + n];
#pragma unroll
    for (int i = 0; i < 20; i++) {
      int o = og + 8 * i;
      const float* wr = (i < 2) ? (wq + o * 128)
                      : (i < 4) ? (wk + (o - 16) * 128)
                                : (wv + (o - 32) * 128);
      acc[i] += wr[c] * xr;
    }
  }
  const size_t pos = (size_t)b * 4096 + n0 + n;
#pragma unroll
  for (int i = 0; i < 20; i++) {
    int o = og + 8 * i;
    if (i < 2)      qT[pos * 16 + o]      = f2bf(acc[i]);
    else if (i < 4) kT[pos * 16 + o - 16] = f2bf(acc[i]);
    else vo[(size_t)b * 524288 + (size_t)(o - 32) * 4096 + n0 + n] = f2bf(acc[i]);
  }
}

// ---------------- Kernel 2: softmax denoms + streaming attn write ----------
// 512 blocks x 256 thr. Block = (b, rb, half): 32 rows, S=rb+1 strips.
// Phase 1 (verified reduction): rowwise sum(exp(E)) -> inv via LDS red[32][4];
// ONE barrier, before any global stores. Also writes inv to ws for pv_kernel.
// Phase 2: NO barriers — each wave recomputes E for strips w, w+4, ... and
// streams fp32 p to attn through L2 (normal stores). Then zero-fills the
// masked cols. Every block writes exactly 32 rows x 4096 cols x 4B = 512 KB,
// so HBM write traffic is byte-balanced across blocks.
__global__ __launch_bounds__(256, 2) void smwrite_kernel(
    const ushort* __restrict__ qT, const ushort* __restrict__ kT,
    float* __restrict__ invw, float* __restrict__ attn) {
  __shared__ float red[32][4];
  const int bx = blockIdx.x;            // 0..511
  const int b = bx & 3;
  const int v_ = bx >> 2;               // 0..127
  const int half = v_ & 1;
  const int u = v_ >> 1;                // 0..63
  const int rb = (u < 32) ? u : 95 - u; // CU-mate load balancing (sum=63)
  const int S = rb + 1;
  const int lane = threadIdx.x & 63;
  const int w = __builtin_amdgcn_readfirstlane((int)(threadIdx.x >> 6));
  const int nblk = rb * 64 + half * 32;
  const int l31 = lane & 31;
  const int h = lane >> 5;
  const int hk = h * 8;
  const ushort* qb = qT + (size_t)b * 65536;
  const ushort* kb = kT + (size_t)b * 65536;
  float* ab = attn + (size_t)b * 16777216;

  const short8 qa = *(const short8*)(qb + (size_t)(nblk + l31) * 16 + hk);
  float16 zero16;
#pragma unroll
  for (int i = 0; i < 16; i++) zero16[i] = 0.f;

  // ---- Phase 1: denominators (identical arithmetic to verified kernel) ----
  float sume[16];
#pragma unroll
  for (int i = 0; i < 16; i++) sume[i] = 0.f;
  for (int s = w; s < S; s += 4) {
    const int m0 = s * 64;
#pragma unroll
    for (int mh = 0; mh < 2; mh++) {
      short8 kf = *(const short8*)(kb + (size_t)(m0 + mh * 32 + l31) * 16 + hk);
      float16 e = __builtin_amdgcn_mfma_f32_32x32x16_bf16(qa, kf, zero16, 0, 0, 0);
#pragma unroll
      for (int r = 0; r < 16; r++) sume[r] += __expf(e[r]);
    }
  }
#pragma unroll
  for (int r = 0; r < 16; r++) {
#pragma unroll
    for (int off = 1; off <= 16; off <<= 1)
      sume[r] += __shfl_xor(sume[r], off, 64);  // sum over 32 cols (l31 group)
  }
  if (l31 == 0) {
#pragma unroll
    for (int r = 0; r < 16; r++) {
      int row = (r & 3) + 8 * (r >> 2) + 4 * h;
      red[row][w] = sume[r];
    }
  }
  __syncthreads();
  float inv_r[16];
#pragma unroll
  for (int r = 0; r < 16; r++) {
    int row = (r & 3) + 8 * (r >> 2) + 4 * h;
    float4 p4 = *(const float4*)&red[row][0];
    inv_r[r] = 1.0f / (p4.x + p4.y + p4.z + p4.w);
  }
  if (w == 0 && l31 == 0) {
#pragma unroll
    for (int r = 0; r < 16; r++) {
      int row = (r & 3) + 8 * (r >> 2) + 4 * h;
      invw[(size_t)b * 4096 + nblk + row] = inv_r[r];
    }
  }

  // ---- Phase 2: barrier-free p stores (normal, L2-buffered) ----
  for (int s = w; s < S; s += 4) {
    const int m0 = s * 64;
#pragma unroll
    for (int mh = 0; mh < 2; mh++) {
      short8 kf = *(const short8*)(kb + (size_t)(m0 + mh * 32 + l31) * 16 + hk);
      float16 e = __builtin_amdgcn_mfma_f32_32x32x16_bf16(qa, kf, zero16, 0, 0, 0);
#pragma unroll
      for (int r = 0; r < 16; r++) {
        int row = (r & 3) + 8 * (r >> 2) + 4 * h;
        float p = __expf(e[r]) * inv_r[r];
        ab[(size_t)(nblk + row) * 4096 + m0 + mh * 32 + l31] = p;
      }
    }
  }

  // ---- Zero-fill masked cols (wave w: rows w*8..w*8+7) ----
  const int M = S * 64;
  const int Z4 = (4096 - M) >> 2;
  const floatx4 z = {0.f, 0.f, 0.f, 0.f};
#pragma unroll
  for (int r = 0; r < 8; r++) {
    floatx4* dst = (floatx4*)(ab + (size_t)(nblk + w * 8 + r) * 4096 + M);
    for (int i4 = lane; i4 < Z4; i4 += 64) dst[i4] = z;
  }
}

// ---------------- Kernel 3: PV accumulate + epilogue (verified R2) ---------
// 512 blocks x 256 thr. Per super-step (4 strips): wave w recomputes E for
// strip s0+w, writes bf16 p to LDS slot w; barrier; all waves run PV MFMA
// over the 4 slots (c-quadrant = wave). inv read from ws.
__global__ __launch_bounds__(256, 2) void pv_kernel(
    const ushort* __restrict__ qT, const ushort* __restrict__ kT,
    const ushort* __restrict__ vws, const float* __restrict__ invw,
    const float* __restrict__ x, const float* __restrict__ g,
    float* __restrict__ out) {
  __shared__ __align__(16) ushort Pt[4][32 * 72];
  const int bx = blockIdx.x;            // 0..511
  const int b = bx & 3;
  const int v_ = bx >> 2;               // 0..127
  const int half = v_ & 1;
  const int u = v_ >> 1;                // 0..63
  const int rb = (u < 32) ? u : 95 - u; // CU-mate load balancing
  const int S = rb + 1;
  const int lane = threadIdx.x & 63;
  const int w = __builtin_amdgcn_readfirstlane((int)(threadIdx.x >> 6));
  const int nblk = rb * 64 + half * 32;
  const int l31 = lane & 31;
  const int h = lane >> 5;
  const int hk = h * 8;
  const ushort* qb = qT + (size_t)b * 65536;
  const ushort* kb = kT + (size_t)b * 65536;
  const ushort* vp = vws + (size_t)b * 524288;

  const short8 qa = *(const short8*)(qb + (size_t)(nblk + l31) * 16 + hk);
  float inv_r[16];
#pragma unroll
  for (int r = 0; r < 16; r++) {
    int row = (r & 3) + 8 * (r >> 2) + 4 * h;
    inv_r[r] = invw[(size_t)b * 4096 + nblk + row];
  }
  float16 zero16;
#pragma unroll
  for (int i = 0; i < 16; i++) zero16[i] = 0.f;

  float16 acc = zero16;
  for (int s0 = 0; s0 < S; s0 += 4) {
    const int sl = (S - s0 < 4) ? (S - s0) : 4;
    if (w < sl) {
      const int m0 = (s0 + w) * 64;
      ushort* Pb = &Pt[w][0];
#pragma unroll
      for (int mh = 0; mh < 2; mh++) {
        short8 kf = *(const short8*)(kb + (size_t)(m0 + mh * 32 + l31) * 16 + hk);
        float16 e = __builtin_amdgcn_mfma_f32_32x32x16_bf16(qa, kf, zero16, 0, 0, 0);
#pragma unroll
        for (int r = 0; r < 16; r++) {
          int row = (r & 3) + 8 * (r >> 2) + 4 * h;
          float p = __expf(e[r]) * inv_r[r];
          Pb[row * 72 + mh * 32 + l31] = f2bf(p);
        }
      }
    }
    __syncthreads();
    for (int ss = 0; ss < sl; ss++) {
      const int m0 = (s0 + ss) * 64;
      const ushort* vrow = vp + (size_t)(w * 32 + l31) * 4096 + m0 + hk;
      const ushort* Pr = &Pt[ss][l31 * 72 + hk];
#pragma unroll
      for (int kk = 0; kk < 4; kk++) {
        short8 a  = *(const short8*)(vrow + kk * 16);
        short8 bf = *(const short8*)(Pr + kk * 16);
        acc = __builtin_amdgcn_mfma_f32_32x32x16_bf16(a, bf, acc, 0, 0, 0);
      }
    }
    __syncthreads();
  }

  // ---- Epilogue: out = gamma * acc + x ----
  const float gamma = g[0];
#pragma unroll
  for (int reg = 0; reg < 16; reg++) {
    int row = (reg & 3) + 8 * (reg >> 2) + 4 * h;  // C/D row map
    int c = w * 32 + row;
    int n = nblk + l31;                            // C/D col = lane&31
    size_t off = (size_t)b * 524288 + (size_t)c * 4096 + n;
    out[off] = gamma * acc[reg] + x[off];
  }
}

extern "C" void kernel_launch(void* const* d_in, const int* in_sizes, int n_in,
                              void* d_out, int out_size, void* d_ws, size_t ws_size,
                              hipStream_t stream) {
  const float* x  = (const float*)d_in[0];
  const float* wq = (const float*)d_in[1];
  const float* bq = (const float*)d_in[2];
  const float* wk = (const float*)d_in[3];
  const float* bk = (const float*)d_in[4];
  const float* wv = (const float*)d_in[5];
  const float* bv = (const float*)d_in[6];
  const float* gm = (const float*)d_in[7];
  float* out  = (float*)d_out;
  float* attn = out + 2097152;            // output 1: attention [4][4096][4096]
  ushort* qTw = (ushort*)d_ws;            // bf16 [4][4096][16]
  ushort* kTw = qTw + 262144;             // bf16 [4][4096][16]
  ushort* vws = qTw + 524288;             // bf16 [4][128][4096]
  float* invw = (float*)(qTw + 2621440);  // fp32 [4][4096]

  qkv_kernel<<<dim3(64, 4), 512, 0, stream>>>(x, wq, bq, wk, bk, wv, bv, qTw, kTw, vws);
  smwrite_kernel<<<dim3(512), 256, 0, stream>>>(qTw, kTw, invw, attn);
  pv_kernel<<<dim3(512), 256, 0, stream>>>(qTw, kTw, vws, invw, x, gm, out);
}

// Round 4
// 353.131 us; speedup vs baseline: 1.1342x; 1.1342x over previous
//
#include <hip/hip_runtime.h>
#include <hip/hip_bf16.h>

// Problem constants: B=4, C=128, Cq=16, W=H=64, N=4096.
// ws layout (ushort): qT bf16 [4][4096][16] @0, kT bf16 [4][4096][16] @262144,
//                     v  bf16 [4][128][4096] @524288
// d_out: out[4][128][4096] fp32, then attention[4][4096][4096] fp32

typedef __attribute__((ext_vector_type(8))) short short8;
typedef __attribute__((ext_vector_type(16))) float float16;

__device__ __forceinline__ ushort f2bf(float f) {
  union { float f; uint u; } v; v.f = f;
  return (ushort)((v.u + 0x7FFFu + ((v.u >> 16) & 1u)) >> 16);  // RNE
}

// Workgroup barrier that waits ONLY on LDS ops (lgkmcnt), NOT on outstanding
// global stores. __syncthreads() emits s_waitcnt vmcnt(0) expcnt(0) lgkmcnt(0)
// which force-drains the 268MB attn store stream at every barrier; the LDS
// P-tile handoff only needs lgkmcnt. Each wave drains its own ds ops to 0
// before arriving; barrier arrival then implies cross-wave LDS visibility.
// sched_barrier(0) fences prevent the compiler from moving ds ops across
// the inline asm (rule #18).
#define LDS_BARRIER()                                             \
  do {                                                            \
    __builtin_amdgcn_sched_barrier(0);                            \
    asm volatile("s_waitcnt lgkmcnt(0)" ::: "memory");            \
    __builtin_amdgcn_sched_barrier(0);                            \
    __builtin_amdgcn_s_barrier();                                 \
    __builtin_amdgcn_sched_barrier(0);                            \
  } while (0)

// ---------------- Kernel 1: QKV projections (unchanged, verified) ----------
__global__ __launch_bounds__(512, 2) void qkv_kernel(
    const float* __restrict__ x,
    const float* __restrict__ wq, const float* __restrict__ bq,
    const float* __restrict__ wk, const float* __restrict__ bk,
    const float* __restrict__ wv, const float* __restrict__ bv,
    ushort* __restrict__ qT, ushort* __restrict__ kT, ushort* __restrict__ vo) {
  __shared__ float xs[128 * 64];
  const int nt = blockIdx.x, b = blockIdx.y;
  const int n0 = nt * 64;
  const float* xb = x + (size_t)b * 524288 + n0;
  for (int idx = threadIdx.x; idx < 8192; idx += 512) {
    int c = idx >> 6, n = idx & 63;
    xs[idx] = xb[(size_t)c * 4096 + n];
  }
  __syncthreads();
  const int n = threadIdx.x & 63;
  const int og = __builtin_amdgcn_readfirstlane((int)(threadIdx.x >> 6)); // 0..7
  float acc[20];
#pragma unroll
  for (int i = 0; i < 20; i++) {
    int o = og + 8 * i;
    acc[i] = (i < 2) ? bq[o] : (i < 4) ? bk[o - 16] : bv[o - 32];
  }
#pragma unroll 4
  for (int c = 0; c < 128; c++) {
    float xr = xs[c * 64 + n];
#pragma unroll
    for (int i = 0; i < 20; i++) {
      int o = og + 8 * i;
      const float* wr = (i < 2) ? (wq + o * 128)
                      : (i < 4) ? (wk + (o - 16) * 128)
                                : (wv + (o - 32) * 128);
      acc[i] += wr[c] * xr;
    }
  }
  const size_t pos = (size_t)b * 4096 + n0 + n;
#pragma unroll
  for (int i = 0; i < 20; i++) {
    int o = og + 8 * i;
    if (i < 2)      qT[pos * 16 + o]      = f2bf(acc[i]);
    else if (i < 4) kT[pos * 16 + o - 16] = f2bf(acc[i]);
    else vo[(size_t)b * 524288 + (size_t)(o - 32) * 4096 + n0 + n] = f2bf(acc[i]);
  }
}

// ---------------- Kernel 2: fused energy + softmax + attn + PV -------------
// Exactly the verified R0 structure; the only change is LDS_BARRIER() in the
// super-step loop so attn stores never drain at barriers and overlap PV MFMA.
__global__ __launch_bounds__(256, 2) void fused_attn_kernel(
    const ushort* __restrict__ qT, const ushort* __restrict__ kT,
    const ushort* __restrict__ vws, const float* __restrict__ x,
    const float* __restrict__ g,
    float* __restrict__ attn, float* __restrict__ out) {
  __shared__ __align__(16) ushort Pt[4][32 * 72];
  __shared__ __align__(16) float red[32][4];
  const int bx = blockIdx.x;            // 0..511
  const int b = bx & 3;
  const int v_ = bx >> 2;               // 0..127
  const int half = v_ & 1;
  const int u = v_ >> 1;                // 0..63
  const int rb = (u < 32) ? u : 95 - u; // CU-mate load balancing
  const int S = rb + 1;
  const int lane = threadIdx.x & 63;
  const int w = __builtin_amdgcn_readfirstlane((int)(threadIdx.x >> 6));
  const int nblk = rb * 64 + half * 32;
  const int l31 = lane & 31;
  const int h = lane >> 5;
  const int hk = h * 8;
  const ushort* qb = qT + (size_t)b * 65536;
  const ushort* kb = kT + (size_t)b * 65536;
  const ushort* vp = vws + (size_t)b * 524288;
  float* ab = attn + (size_t)b * 16777216;

  // q A-fragment for this block's 32 rows: A[n=l31][d=hk..hk+7] — 4 VGPRs.
  const short8 qa = *(const short8*)(qb + (size_t)(nblk + l31) * 16 + hk);

  float16 zero16;
#pragma unroll
  for (int i = 0; i < 16; i++) zero16[i] = 0.f;

  // ---- Phase 1: denominators ----
  float sume[16];
#pragma unroll
  for (int i = 0; i < 16; i++) sume[i] = 0.f;
  for (int s = w; s < S; s += 4) {
    const int m0 = s * 64;
#pragma unroll
    for (int mh = 0; mh < 2; mh++) {
      short8 kf = *(const short8*)(kb + (size_t)(m0 + mh * 32 + l31) * 16 + hk);
      float16 e = __builtin_amdgcn_mfma_f32_32x32x16_bf16(qa, kf, zero16, 0, 0, 0);
#pragma unroll
      for (int r = 0; r < 16; r++) sume[r] += __expf(e[r]);
    }
  }
#pragma unroll
  for (int r = 0; r < 16; r++) {
#pragma unroll
    for (int off = 1; off <= 16; off <<= 1)
      sume[r] += __shfl_xor(sume[r], off, 64);  // sum over 32 cols (l31 group)
  }
  if (l31 == 0) {
#pragma unroll
    for (int r = 0; r < 16; r++) {
      int row = (r & 3) + 8 * (r >> 2) + 4 * h;
      red[row][w] = sume[r];
    }
  }
  __syncthreads();
  float inv[16];
#pragma unroll
  for (int r = 0; r < 16; r++) {
    int row = (r & 3) + 8 * (r >> 2) + 4 * h;
    float4 p4 = *(const float4*)&red[row][0];
    inv[r] = 1.0f / (p4.x + p4.y + p4.z + p4.w);
  }

  // ---- Phase 2: attn write + PV accumulate ----
  float16 acc = zero16;
  for (int s0 = 0; s0 < S; s0 += 4) {
    const int sl = (S - s0 < 4) ? (S - s0) : 4;
    if (w < sl) {
      const int m0 = (s0 + w) * 64;
      ushort* Pb = &Pt[w][0];
#pragma unroll
      for (int mh = 0; mh < 2; mh++) {
        short8 kf = *(const short8*)(kb + (size_t)(m0 + mh * 32 + l31) * 16 + hk);
        float16 e = __builtin_amdgcn_mfma_f32_32x32x16_bf16(qa, kf, zero16, 0, 0, 0);
#pragma unroll
        for (int r = 0; r < 16; r++) {
          int row = (r & 3) + 8 * (r >> 2) + 4 * h;
          float p = __expf(e[r]) * inv[r];
          ab[(size_t)(nblk + row) * 4096 + m0 + mh * 32 + l31] = p;
          Pb[row * 72 + mh * 32 + l31] = f2bf(p);
        }
      }
    }
    LDS_BARRIER();   // waits LDS only; attn stores stay in flight
    for (int ss = 0; ss < sl; ss++) {
      const int m0 = (s0 + ss) * 64;
      const ushort* vrow = vp + (size_t)(w * 32 + l31) * 4096 + m0 + hk;
      const ushort* Pr = &Pt[ss][l31 * 72 + hk];
#pragma unroll
      for (int kk = 0; kk < 4; kk++) {
        short8 a  = *(const short8*)(vrow + kk * 16);
        short8 bf = *(const short8*)(Pr + kk * 16);
        acc = __builtin_amdgcn_mfma_f32_32x32x16_bf16(a, bf, acc, 0, 0, 0);
      }
    }
    LDS_BARRIER();   // protects Pt overwrite; again no vmcnt drain
  }

  // ---- Epilogue: zero-fill masked attn region (wave w: rows w*8..w*8+7) ----
  const int M = S * 64;
  const int Z4 = (4096 - M) >> 2;
  const float4 z = make_float4(0.f, 0.f, 0.f, 0.f);
#pragma unroll
  for (int r = 0; r < 8; r++) {
    float4* dst = (float4*)(ab + (size_t)(nblk + w * 8 + r) * 4096 + M);
    for (int i4 = lane; i4 < Z4; i4 += 64) dst[i4] = z;
  }

  // ---- Epilogue: out = gamma * acc + x ----
  const float gamma = g[0];
#pragma unroll
  for (int reg = 0; reg < 16; reg++) {
    int row = (reg & 3) + 8 * (reg >> 2) + 4 * h;  // C/D row map
    int c = w * 32 + row;
    int n = nblk + l31;                            // C/D col = lane&31
    size_t off = (size_t)b * 524288 + (size_t)c * 4096 + n;
    out[off] = gamma * acc[reg] + x[off];
  }
}

extern "C" void kernel_launch(void* const* d_in, const int* in_sizes, int n_in,
                              void* d_out, int out_size, void* d_ws, size_t ws_size,
                              hipStream_t stream) {
  const float* x  = (const float*)d_in[0];
  const float* wq = (const float*)d_in[1];
  const float* bq = (const float*)d_in[2];
  const float* wk = (const float*)d_in[3];
  const float* bk = (const float*)d_in[4];
  const float* wv = (const float*)d_in[5];
  const float* bv = (const float*)d_in[6];
  const float* gm = (const float*)d_in[7];
  float* out  = (float*)d_out;
  float* attn = out + 2097152;            // output 1: attention [4][4096][4096]
  ushort* qTw = (ushort*)d_ws;            // bf16 [4][4096][16]
  ushort* kTw = qTw + 262144;             // bf16 [4][4096][16]
  ushort* vws = qTw + 524288;             // bf16 [4][128][4096]

  qkv_kernel<<<dim3(64, 4), 512, 0, stream>>>(x, wq, bq, wk, bk, wv, bv, qTw, kTw, vws);
  fused_attn_kernel<<<dim3(512), 256, 0, stream>>>(qTw, kTw, vws, x, gm, attn, out);
}